// Round 4
// baseline (864.570 us; speedup 1.0000x reference)
//
#include <hip/hip_runtime.h>
#include <stdint.h>

// Problem constants
#define T_STEPS 512
#define HID     64
#define INP     10
#define KS      88              // k-stride (elements) of packed W layout [t][n][KS]
#define HS      72              // h LDS row stride (elems)
#define WT_ELEMS (HID*KS)       // 5632 bf16 per step
#define WT_BYTES (WT_ELEMS*2)   // 11264 B per step
#define WS_SLOTS (WT_BYTES/16)  // 704 real 16B slots

// Wave-local pipeline geometry
#define LOOK   6                // DMA lookahead (steps)
#define RING   8                // LDS ring depth (power of 2)
#define WSLOTP 768              // padded 16B slots per ring entry (2 waves x 6 instr x 64)
#define WR_SH  (WSLOTP*8)       // shorts per W ring entry = 6144 (12288 B)
#define XR_DW  384              // dwords per x ring entry (2 waves x 192)

typedef float  f32x4  __attribute__((ext_vector_type(4)));
typedef short  s16x8  __attribute__((ext_vector_type(8)));
typedef __bf16 bf16x8 __attribute__((ext_vector_type(8)));

typedef const __attribute__((address_space(1))) unsigned int* gp_t;
typedef __attribute__((address_space(3))) unsigned int*       lp_t;

__device__ __forceinline__ short f2bf(float f) {          // manual RNE (prep pass)
    unsigned u = __builtin_bit_cast(unsigned, f);
    u = (u + 0x7FFFu + ((u >> 16) & 1u)) >> 16;
    return (short)u;
}
__device__ __forceinline__ short f2bfh(float f) {         // hw cvt (hot loop)
    return __builtin_bit_cast(short, (__bf16)f);
}
__device__ __forceinline__ float bf2f(short s) {
    unsigned u = ((unsigned)(unsigned short)s) << 16;
    return __builtin_bit_cast(float, u);
}

// ---------------------------------------------------------------------------
// Pre-pass (unchanged from r3): pack [W_hh[t];W_xh[t];0] transposed into
// bf16 Wc[t][n][k], k-stride 88. LDS stride 65 -> conflict-free transpose.
// ---------------------------------------------------------------------------
__global__ __launch_bounds__(256) void prep_w(const float* __restrict__ Wxh,
                                              const float* __restrict__ Whh,
                                              short* __restrict__ Wc) {
    __shared__ float s_hh[64 * 65];
    __shared__ float s_xh[INP * 65];
    const int t = blockIdx.x, tid = threadIdx.x;
    for (int i = tid; i < 64 * 64; i += 256)
        s_hh[(i >> 6) * 65 + (i & 63)] = Whh[t * 4096 + i];
    for (int i = tid; i < INP * 64; i += 256)
        s_xh[(i >> 6) * 65 + (i & 63)] = Wxh[t * (INP * 64) + i];
    __syncthreads();
    short* dst = Wc + (size_t)t * WT_ELEMS;
    for (int i = tid; i < WT_ELEMS; i += 256) {
        const int n = i / KS, k = i % KS;
        float v = 0.f;
        if (k < 64)      v = s_hh[k * 65 + n];
        else if (k < 74) v = s_xh[(k - 64) * 65 + n];
        dst[i] = f2bf(v);
    }
}

// ---------------------------------------------------------------------------
// Wave-local recurrence. 256 blocks x 128 threads (2 waves), 16 samples/wave.
// Each wave computes its samples' FULL h-update (4 N-tiles x 3 K-chunks = 12
// MFMA/step); the C->A transpose goes through wave-PRIVATE LDS (in-wave
// lgkmcnt order only). NO per-step block barrier. Shared W ring (8 tiles,
// lookahead 6, halves staged per wave) + per-wave x ring are published by a
// barrier every 2 steps with a COUNTED s_waitcnt vmcnt(36) -- loads stay in
// flight across barriers (9 DMA/step/wave, 4 steps' worth outstanding).
// ---------------------------------------------------------------------------
__global__ __launch_bounds__(128) void rnn_main(const float* __restrict__ X,
                                                const int* __restrict__ L,
                                                const short* __restrict__ Wc,
                                                const float* __restrict__ Wlin,
                                                const float* __restrict__ blin,
                                                float* __restrict__ out) {
    __shared__ __attribute__((aligned(16))) short Wr[RING][WR_SH];     // 98304 B
    __shared__ __attribute__((aligned(16))) float Xr[RING][XR_DW];     // 12288 B
    __shared__ __attribute__((aligned(16))) short hbuf[2][16 * HS];    //  4608 B
    __shared__ int len_s[32];                                          //   128 B

    const int tid  = threadIdx.x;
    const int lane = tid & 63;
    const int w    = tid >> 6;        // wave 0/1
    const int q    = lane >> 4;
    const int l    = lane & 15;
    const long long sb = (long long)blockIdx.x * 32 + w * 16;  // wave's sample base

    // ---- per-lane loop-invariant DMA source offsets ----
    int voffW[6];
#pragma unroll
    for (int i = 0; i < 6; ++i) {
        int s = w * 384 + i * 64 + lane;          // padded slot id 0..767
        if (s > WS_SLOTS - 1) s = WS_SLOTS - 1;   // clamp junk tail (never read)
        voffW[i] = s * 16;
    }
    int voffX[3];
#pragma unroll
    for (int i = 0; i < 3; ++i) {
        int d = i * 64 + lane;                    // dword id 0..191
        if (d > 159) d = 159;                     // clamp junk tail
        const int s = d / 10, e = d - 10 * s;
        voffX[i] = s * (T_STEPS * INP * 4) + e * 4;
    }
    const char* xbase = (const char*)X + (size_t)sb * (T_STEPS * INP * 4);

    // ---- lens via LDS bounce: no pending global->reg loads live into loop ----
    if (lane < 16) len_s[w * 16 + lane] = L[sb + lane];
    for (int i = lane; i < 16 * HS; i += 64) hbuf[w][i] = 0;   // zero own h
    int len4[4];
#pragma unroll
    for (int r = 0; r < 4; ++r) len4[r] = len_s[w * 16 + q * 4 + r];  // in-wave lgkm

    // ---- DMA issue (all fire-and-forget, counted by own wave's vmcnt) ----
    auto issue_x = [&](int tw, int slot) {
        const char* src = xbase + (size_t)tw * (INP * 4);
        char* dst = (char*)&Xr[slot][w * 192];
#pragma unroll
        for (int i = 0; i < 3; ++i)
            __builtin_amdgcn_global_load_lds((gp_t)(src + voffX[i]),
                                             (lp_t)(dst + i * 256), 4, 0, 0);
    };
    auto issue_w = [&](int tw, int slot) {
        const char* src = (const char*)Wc + (size_t)tw * WT_BYTES;
        char* dst = (char*)&Wr[slot][0] + w * 6144;
#pragma unroll
        for (int i = 0; i < 6; ++i)
            __builtin_amdgcn_global_load_lds((gp_t)(src + voffW[i]),
                                             (lp_t)(dst + i * 1024), 16, 0, 0);
    };

    // ---- prologue: issue tiles 0..5 (x then W each step; 9 instrs/step) ----
#pragma unroll
    for (int k = 0; k < LOOK; ++k) { issue_x(k, k); issue_w(k, k); }
    // outstanding = 54; loop-top wait(36) completes tiles 0,1.

    float hc[4][4];
#pragma unroll
    for (int nt = 0; nt < 4; ++nt)
#pragma unroll
        for (int r = 0; r < 4; ++r) hc[nt][r] = 0.f;

    const short* hrow = &hbuf[w][l * HS];

    for (int it = 0; it < T_STEPS / 8; ++it) {
#pragma unroll
        for (int k = 0; k < 8; ++k) {
            const int t = it * 8 + k;

            if ((k & 1) == 0) {
                // phase boundary: counted wait publishes tiles t, t+1 (issued
                // >=5 steps ago); tiles t+2..t+5 stay in flight (36 = 4x9).
                asm volatile("s_waitcnt vmcnt(36)" ::: "memory");
                __builtin_amdgcn_s_barrier();
            }

            // 1) issue tile t+6 into slot (t+6)&7  (9 DMA instrs, fixed order)
            const int tw = (t + LOOK < T_STEPS) ? (t + LOOK) : (T_STEPS - 1);
            issue_x(tw, (k + LOOK) & 7);
            issue_w(tw, (k + LOOK) & 7);

            // 2) B fragments: full W tile from ring slot k
            s16x8 bf[4][3];
#pragma unroll
            for (int nt = 0; nt < 4; ++nt)
#pragma unroll
                for (int c = 0; c < 3; ++c)
                    bf[nt][c] = *(const s16x8*)&Wr[k][(nt * 16 + l) * KS + c * 32 + q * 8];

            // 3) A fragments: h (own LDS) + x (own ring region, fp32->bf16)
            const s16x8 a0 = *(const s16x8*)(hrow + q * 8);
            const s16x8 a1 = *(const s16x8*)(hrow + 32 + q * 8);
            const float2* xp = (const float2*)&Xr[k][w * 192 + l * 10 + q * 8];
            const float2 p0 = xp[0], p1 = xp[1], p2 = xp[2], p3 = xp[3];
            const float xv[8] = {p0.x, p0.y, p1.x, p1.y, p2.x, p2.y, p3.x, p3.y};
            s16x8 a2;
#pragma unroll
            for (int j = 0; j < 8; ++j)
                a2[j] = (q * 8 + j < INP) ? f2bfh(xv[j]) : (short)0;

            // 4) 12 MFMA: 4 N-tiles x 3 accumulated K-chunks
            f32x4 acc[4];
#pragma unroll
            for (int nt = 0; nt < 4; ++nt) {
                f32x4 z = {0.f, 0.f, 0.f, 0.f};
                acc[nt] = __builtin_amdgcn_mfma_f32_16x16x32_bf16(
                    __builtin_bit_cast(bf16x8, a0), __builtin_bit_cast(bf16x8, bf[nt][0]), z, 0, 0, 0);
                acc[nt] = __builtin_amdgcn_mfma_f32_16x16x32_bf16(
                    __builtin_bit_cast(bf16x8, a1), __builtin_bit_cast(bf16x8, bf[nt][1]), acc[nt], 0, 0, 0);
                acc[nt] = __builtin_amdgcn_mfma_f32_16x16x32_bf16(
                    __builtin_bit_cast(bf16x8, a2), __builtin_bit_cast(bf16x8, bf[nt][2]), acc[nt], 0, 0, 0);
            }

            // 5) tanh + freeze + h write-back (own LDS; in-wave order only)
#pragma unroll
            for (int nt = 0; nt < 4; ++nt)
#pragma unroll
                for (int r = 0; r < 4; ++r) {
                    const float a  = acc[nt][r];
                    const float e  = __expf(2.f * a);
                    const float th = 1.f - 2.f * __builtin_amdgcn_rcpf(e + 1.f);
                    hc[nt][r] = (t < len4[r]) ? th : hc[nt][r];
                    hbuf[w][(q * 4 + r) * HS + nt * 16 + l] = f2bfh(hc[nt][r]);
                }
        }
    }

    asm volatile("s_waitcnt vmcnt(0)" ::: "memory");   // drain tail prefetches

    // ---- epilogue: out[s] = h[s] . W_lin + b_lin  (own wave, no barrier) ----
    const s16x8 h0 = *(const s16x8*)&hbuf[w][l * HS + q * 16];
    const s16x8 h1 = *(const s16x8*)&hbuf[w][l * HS + q * 16 + 8];
    float v = 0.f;
#pragma unroll
    for (int j = 0; j < 8; ++j) {
        v += bf2f(h0[j]) * Wlin[q * 16 + j];
        v += bf2f(h1[j]) * Wlin[q * 16 + 8 + j];
    }
    v += __shfl_xor(v, 16);
    v += __shfl_xor(v, 32);
    if (q == 0) out[sb + l] = v + blin[0];
}

extern "C" void kernel_launch(void* const* d_in, const int* in_sizes, int n_in,
                              void* d_out, int out_size, void* d_ws, size_t ws_size,
                              hipStream_t stream) {
    const float* X    = (const float*)d_in[0];      // [B,T,10] fp32
    const int*   L    = (const int*)d_in[1];        // [B] int32
    const float* Wxh  = (const float*)d_in[2];      // [T,10,64]
    const float* Whh  = (const float*)d_in[3];      // [T,64,64]
    const float* Wlin = (const float*)d_in[4];      // [64,1]
    const float* blin = (const float*)d_in[5];      // [1]
    float*       out  = (float*)d_out;              // [B,1] fp32
    short*       Wc   = (short*)d_ws;               // 512*5632 bf16 = 5.77 MB

    prep_w<<<T_STEPS, 256, 0, stream>>>(Wxh, Whh, Wc);
    rnn_main<<<8192 / 32, 128, 0, stream>>>(X, L, Wc, Wlin, blin, out);
}